// Round 3
// baseline (396.713 us; speedup 1.0000x reference)
//
#include <hip/hip_runtime.h>
#include <math.h>

#define T_IN     2048
#define T_OUT    2276
#define NTH      256
#define CHUNK    9            // 256*9 = 2304 >= 2276
#define NPAD     (NTH*CHUNK)
#define RATE     0.9f
#define TWO_PI_F 6.2831855f   // float32(2*pi)

__global__ __launch_bounds__(NTH)
void phase_vocoder_kernel(const float* __restrict__ xr,
                          const float* __restrict__ xi,
                          float* __restrict__ out,
                          int n_rows, long long out_floats)
{
    __shared__ float  ph_lds[NPAD];    // phase diffs; reused as out_re
    __shared__ float  mag_lds[NPAD];   // mags; reused as out_im
    __shared__ double stot[NTH];       // per-thread totals for block scan
    __shared__ float  ang_first;

    const int row = blockIdx.x;
    if (row >= n_rows) return;
    const float* __restrict__ re_row = xr + (size_t)row * T_IN;
    const float* __restrict__ im_row = xi + (size_t)row * T_IN;
    const int tid = threadIdx.x;

    if (tid == 0) {
        ang_first = atan2f(im_row[0], re_row[0]);  // jnp.angle(spec[...,0])
    }

    // ---- Step A: coalesced per-frame phase diff + magnitude ----
    for (int t = tid; t < NPAD; t += NTH) {
        float p = 0.0f, mgv = 0.0f;
        if (t < T_OUT) {
            float ts    = (float)t * RATE;   // bitwise == np.arange f32 fill
            int   i0    = (int)ts;           // ts >= 0 -> trunc == floor
            float alpha = ts - (float)i0;    // == mod(ts, 1)
            float re0 = re_row[i0], im0 = im_row[i0];
            float re1 = 0.0f, im1 = 0.0f;
            if (i0 + 1 < T_IN) { re1 = re_row[i0 + 1]; im1 = im_row[i0 + 1]; }
            float a0 = atan2f(im0, re0);
            float a1 = atan2f(im1, re1);     // atan2(0,0)=0 matches angle(0)
            float n0 = sqrtf(re0 * re0 + im0 * im0);
            float n1 = sqrtf(re1 * re1 + im1 * im1);
            float d  = a1 - a0;
            d = d - TWO_PI_F * rintf(d / TWO_PI_F);  // half-to-even = np.round
            p = d;
            mgv = alpha * n1 + (1.0f - alpha) * n0;
        }
        ph_lds[t]  = p;
        mag_lds[t] = mgv;
    }
    __syncthreads();

    // ---- Step B: block scan of phase_cat = [ang_first, ph[0:T_OUT-1]] ----
    const int base = tid * CHUNK;
    float v[CHUNK], m[CHUNK];
#pragma unroll
    for (int j = 0; j < CHUNK; ++j) {
        int t = base + j;
        float pc = 0.0f;
        if (t < T_OUT) pc = (t == 0) ? ang_first : ph_lds[t - 1];
        v[j] = pc;
        m[j] = mag_lds[t];   // t < NPAD always; zeros beyond T_OUT
    }
    __syncthreads();

    // thread-local inclusive scan in double
    double s[CHUNK];
    double run = 0.0;
#pragma unroll
    for (int j = 0; j < CHUNK; ++j) { run += (double)v[j]; s[j] = run; }

    // block-level inclusive scan of per-thread totals via LDS (Hillis-Steele)
    double incl = run;
    stot[tid] = incl;
    __syncthreads();
    for (int off = 1; off < NTH; off <<= 1) {
        double add = 0.0;
        if (tid >= off) add = stot[tid - off];
        __syncthreads();
        incl += add;
        stot[tid] = incl;
        __syncthreads();
    }
    const double pre = incl - run;   // exclusive prefix for this thread

    // ---- epilogue: mag * exp(i * phase_acc), stash into LDS ----
#pragma unroll
    for (int j = 0; j < CHUNK; ++j) {
        float acc = (float)(pre + s[j]);
        float sn, cs;
        sincosf(acc, &sn, &cs);
        int t = base + j;
        ph_lds[t]  = m[j] * cs;    // real part
        mag_lds[t] = m[j] * sn;    // imag part
    }
    __syncthreads();

    // ---- PLANAR complex store: [real plane (B,F,T_out)][imag plane] ----
    const long long nplane  = (long long)n_rows * T_OUT;
    const long long rowbase = (long long)row * T_OUT;
    for (int t = tid; t < T_OUT; t += NTH) {
        long long o = rowbase + t;
        if (o < out_floats)          out[o]          = ph_lds[t];
        if (nplane + o < out_floats) out[nplane + o] = mag_lds[t];
    }
}

extern "C" void kernel_launch(void* const* d_in, const int* in_sizes, int n_in,
                              void* d_out, int out_size, void* d_ws, size_t ws_size,
                              hipStream_t stream) {
    const float* xr = (const float*)d_in[0];
    const float* xi = (const float*)d_in[1];
    float* out = (float*)d_out;
    const int n_rows = in_sizes[0] / T_IN;   // 16 * 1025 = 16400
    phase_vocoder_kernel<<<n_rows, NTH, 0, stream>>>(xr, xi, out, n_rows,
                                                     (long long)out_size);
}

// Round 4
// 393.223 us; speedup vs baseline: 1.0089x; 1.0089x over previous
//
#include <hip/hip_runtime.h>
#include <math.h>

#define T_IN   2048
#define T_OUT  2276
#define NTH    256
#define CHUNK  9              // 256*9 = 2304 >= 2276
#define NPAD   (NTH*CHUNK)
#define NFR    2050           // input frames + zero pad (need up to idx 2048)
#define RATE   0.9f
#define TWO_PI_F  6.2831855f
#define INV_2PI_F 0.15915494f
#define INV_2PI_D 0.15915494309189535

// atan2 via octant reduction + Cephes deg-9 poly. Max err ~3e-7 rad.
// Errors telescope in the downstream cumsum (adjacent diffs share angles).
__device__ __forceinline__ float fast_atan2f(float y, float x) {
    float ax = fabsf(x), ay = fabsf(y);
    float mx = fmaxf(ax, ay);
    float mn = fminf(ax, ay);
    bool big = mn > 0.41421357f * mx;          // reduce to |u| <= tan(pi/8)
    float num = big ? (mn - mx) : mn;
    float den = big ? (mn + mx) : mx;
    den = (mx == 0.0f) ? 1.0f : den;           // atan2(0,0) -> 0, no NaN
    float u = num * __builtin_amdgcn_rcpf(den);
    float s = u * u;
    float p = fmaf(s, fmaf(s, fmaf(s, 8.05374449538e-2f, -1.38776856032e-1f),
                           1.99777106478e-1f), -3.33329491539e-1f);
    float r = fmaf(u * s, p, u);
    r = big ? (0.78539816f + r) : r;
    r = (ay > ax) ? (1.57079633f - r) : r;
    r = (x < 0.0f) ? (3.14159265f - r) : r;
    return copysignf(r, y);
}

__global__ __launch_bounds__(NTH)
void phase_vocoder_kernel(const float* __restrict__ xr,
                          const float* __restrict__ xi,
                          float* __restrict__ out,
                          int n_rows, long long out_floats)
{
    __shared__ float  ang[NFR];        // per-input-frame angle
    __shared__ float  nrm[NFR];        // per-input-frame magnitude
    __shared__ float  ph_lds[NPAD];    // wrapped phase diffs; reused as out_re
    __shared__ float  mag_lds[NPAD];   // interp mags;        reused as out_im
    __shared__ double stot[NTH];       // per-thread totals for block scan

    const int row = blockIdx.x;
    if (row >= n_rows) return;
    const float* __restrict__ re_row = xr + (size_t)row * T_IN;
    const float* __restrict__ im_row = xi + (size_t)row * T_IN;
    const int tid = threadIdx.x;

    // ---- Fill: angle/norm of each INPUT frame (2048 atan2 instead of 4552) ----
    for (int i = tid; i < NFR; i += NTH) {
        float re = 0.0f, im = 0.0f;
        if (i < T_IN) { re = re_row[i]; im = im_row[i]; }
        ang[i] = fast_atan2f(im, re);                       // angle(0)=0 at pad
        nrm[i] = __builtin_amdgcn_sqrtf(fmaf(re, re, im * im));
    }
    __syncthreads();

    // ---- Step A (strided): wrapped phase diff + interpolated magnitude ----
    for (int t = tid; t < NPAD; t += NTH) {
        float p = 0.0f, mgv = 0.0f;
        if (t < T_OUT) {
            float ts    = (float)t * RATE;     // f32 == np.arange fill
            int   i0    = (int)ts;             // trunc == floor (ts >= 0)
            float alpha = ts - (float)i0;      // == mod(ts, 1)
            float a0 = ang[i0], a1 = ang[i0 + 1];
            float n0 = nrm[i0], n1 = nrm[i0 + 1];
            float d  = a1 - a0;
            float k  = rintf(d * INV_2PI_F);   // boundary flips => exact 2pi, harmless
            p  = fmaf(-k, TWO_PI_F, d);
            mgv = alpha * n1 + (1.0f - alpha) * n0;
        }
        ph_lds[t]  = p;
        mag_lds[t] = mgv;
    }
    __syncthreads();

    // ---- Step B: chunk-load phase_cat = [ang[0], ph[0:T_OUT-1]] in REVOLUTIONS ----
    const int base = tid * CHUNK;
    double s[CHUNK];
    float  m[CHUNK];
    double run = 0.0;
#pragma unroll
    for (int j = 0; j < CHUNK; ++j) {
        int t = base + j;
        float pc = 0.0f;
        if (t < T_OUT) pc = (t == 0) ? ang[0] : ph_lds[t - 1];
        m[j] = mag_lds[t];
        run += (double)pc * INV_2PI_D;         // radians -> revolutions
        s[j] = run;
    }
    __syncthreads();

    // block-level inclusive scan of per-thread totals (Hillis-Steele, LDS)
    double incl = run;
    stot[tid] = incl;
    __syncthreads();
    for (int off = 1; off < NTH; off <<= 1) {
        double add = 0.0;
        if (tid >= off) add = stot[tid - off];
        __syncthreads();
        incl += add;
        stot[tid] = incl;
        __syncthreads();
    }
    const double pre = incl - run;             // exclusive prefix

    // ---- epilogue: frac revolution -> HW sin/cos; stash re/im in LDS ----
#pragma unroll
    for (int j = 0; j < CHUNK; ++j) {
        double acc  = pre + s[j];              // revolutions, |acc| < ~1200
        float  frac = (float)(acc - rint(acc));// [-0.5, 0.5]
        float  sn = __builtin_amdgcn_sinf(frac);  // v_sin_f32: sin(x * 2pi)
        float  cs = __builtin_amdgcn_cosf(frac);
        int t = base + j;
        ph_lds[t]  = m[j] * cs;                // real
        mag_lds[t] = m[j] * sn;                // imag
    }
    __syncthreads();

    // ---- PLANAR complex store: [real plane (rows,T_OUT)][imag plane] ----
    const long long nplane  = (long long)n_rows * T_OUT;
    const long long rowbase = (long long)row * T_OUT;
    for (int t = tid; t < T_OUT; t += NTH) {
        long long o = rowbase + t;
        if (o < out_floats)          out[o]          = ph_lds[t];
        if (nplane + o < out_floats) out[nplane + o] = mag_lds[t];
    }
}

extern "C" void kernel_launch(void* const* d_in, const int* in_sizes, int n_in,
                              void* d_out, int out_size, void* d_ws, size_t ws_size,
                              hipStream_t stream) {
    const float* xr = (const float*)d_in[0];
    const float* xi = (const float*)d_in[1];
    float* out = (float*)d_out;
    const int n_rows = in_sizes[0] / T_IN;     // 16 * 1025 = 16400
    phase_vocoder_kernel<<<n_rows, NTH, 0, stream>>>(xr, xi, out, n_rows,
                                                     (long long)out_size);
}